// Round 2
// baseline (1701.201 us; speedup 1.0000x reference)
//
#include <hip/hip_runtime.h>

typedef _Float16 f16;
typedef _Float16 f16x8 __attribute__((ext_vector_type(8)));
typedef _Float16 f16x4 __attribute__((ext_vector_type(4)));
typedef float f32x4 __attribute__((ext_vector_type(4)));

#define MFMA16(a, b, c) __builtin_amdgcn_mfma_f32_16x16x32_f16((a), (b), (c), 0, 0, 0)
#define CLAMP01(x) __builtin_amdgcn_fmed3f((x), 0.0f, 1.0f)

constexpr int BATCH = 16384;
constexpr int H     = 256;
constexpr int IN    = 784;
constexpr int OUT   = 10;
constexpr int TSTEP = 50;
constexpr int BM    = 16;    // batch rows per block
constexpr int NTHR  = 512;   // 8 waves; wave w owns h in [32w, 32w+32)
constexpr int SROW  = 264;   // padded f16 row stride (33 x 16B quads -> conflict-free b128)
constexpr int S0ROW = 40;    // padded f16 row stride for s0 tile (K padded 10->32)
constexpr int DROW  = 800;   // padded f16 row stride for data staging (784 -> 800)

// LDS pool offsets (f16 units). Data staging [16][800]=12800 f16 overlays the
// state buffers (not yet live during the x2 prologue). Epilogue f32 transpose
// buffer (16x264 f32 = 8448 f16) also overlays the state buffers.
constexpr int OFF_S1_0 = 0;
constexpr int OFF_S1_1 = BM * SROW;            // 4224
constexpr int OFF_S2_0 = 2 * BM * SROW;        // 8448
constexpr int OFF_S2_1 = 3 * BM * SROW;        // 12672
constexpr int OFF_S0_0 = 4 * BM * SROW;        // 16896
constexpr int OFF_S0_1 = OFF_S0_0 + BM * S0ROW;
constexpr int OFF_W0N  = OFF_S0_1 + BM * S0ROW; // 18176
constexpr int POOL_F16 = OFF_W0N + 16 * SROW;   // 22400 f16 = 44800 B

__global__ __launch_bounds__(NTHR, 4) void ep_step_kernel(
    const float* __restrict__ data, const float* __restrict__ s0_in,
    const float* __restrict__ s1_in, const float* __restrict__ s2_in,
    const float* __restrict__ W0, const float* __restrict__ b0,
    const float* __restrict__ W2, const float* __restrict__ b2,
    const float* __restrict__ W4, const float* __restrict__ b4,
    float* __restrict__ out)
{
    __shared__ __align__(16) f16 pool[POOL_F16];

    const int tid  = threadIdx.x;
    const int wave = tid >> 6;
    const int lane = tid & 63;
    const int q    = lane >> 4;   // quad 0..3
    const int l16  = lane & 15;
    const int m0   = blockIdx.x * BM;
    const int h0   = wave * 32;   // this wave's 32-column h slab (2 tiles of 16)

    // ---- phase 1: stage rho(data)->f16 LDS (overlay), W0-natural tile, zero s0 bufs ----------
    for (int i = tid; i < BM * (DROW / 4); i += NTHR) {
        int m  = i / (DROW / 4);
        int k4 = (i % (DROW / 4)) * 4;
        f16x4 p = {(f16)0.f, (f16)0.f, (f16)0.f, (f16)0.f};
        if (k4 < IN) {
            f32x4 v = *(const f32x4*)(data + (size_t)(m0 + m) * IN + k4);
            #pragma unroll
            for (int j = 0; j < 4; ++j) p[j] = (f16)CLAMP01(v[j]);
        }
        *(f16x4*)&pool[m * DROW + k4] = p;
    }
    for (int i = tid; i < 16 * SROW; i += NTHR) {
        int o = i / SROW, k = i % SROW;
        pool[OFF_W0N + i] = (o < OUT && k < H) ? (f16)W0[o * H + k] : (f16)0.f;
    }
    for (int i = tid; i < 2 * BM * S0ROW; i += NTHR) pool[OFF_S0_0 + i] = (f16)0.f;
    __syncthreads();

    // ---- phase 2: persistent register weight fragments ----------------------------------------
    f16x8 wB[2][8];  // A'[h][k] = W2[h][k]   (for out1 = s2 @ W2^T)
    f16x8 wA[2][8];  // A'[h][k] = W2[k][h]   (for out2 = s1 @ W2)
    #pragma unroll
    for (int ht = 0; ht < 2; ++ht) {
        int h = h0 + ht * 16 + l16;
        #pragma unroll
        for (int kk = 0; kk < 8; ++kk) {
            int kb = kk * 32 + q * 8;
            f32x4 u0 = *(const f32x4*)(W2 + h * H + kb);
            f32x4 u1 = *(const f32x4*)(W2 + h * H + kb + 4);
            f16x8 wb;
            #pragma unroll
            for (int j = 0; j < 4; ++j) { wb[j] = (f16)u0[j]; wb[j + 4] = (f16)u1[j]; }
            wB[ht][kk] = wb;
            f16x8 wa;
            #pragma unroll
            for (int j = 0; j < 8; ++j) wa[j] = (f16)W2[(kb + j) * H + h];
            wA[ht][kk] = wa;
        }
    }
    f16x8 w0c[2];  // A'[h][o] = W0[o][h], K padded 10->32
    #pragma unroll
    for (int ht = 0; ht < 2; ++ht) {
        int h = h0 + ht * 16 + l16;
        #pragma unroll
        for (int j = 0; j < 8; ++j) {
            int o = q * 8 + j;
            w0c[ht][j] = (o < OUT) ? (f16)W0[o * H + h] : (f16)0.f;
        }
    }

    // x2 = rho(data) @ W4^T + b4 (transposed C[h][m]), persistent in registers
    f32x4 x2a[2] = {{0.f, 0.f, 0.f, 0.f}, {0.f, 0.f, 0.f, 0.f}};
    for (int kk = 0; kk < 25; ++kk) {
        int kb = kk * 32 + q * 8;
        f16x8 bd = *(const f16x8*)&pool[l16 * DROW + kb];
        #pragma unroll
        for (int ht = 0; ht < 2; ++ht) {
            int h = h0 + ht * 16 + l16;
            f16x8 wa4;
            if (kk < 24) {
                f32x4 u0 = *(const f32x4*)(W4 + (size_t)h * IN + kb);
                f32x4 u1 = *(const f32x4*)(W4 + (size_t)h * IN + kb + 4);
                #pragma unroll
                for (int j = 0; j < 4; ++j) { wa4[j] = (f16)u0[j]; wa4[j + 4] = (f16)u1[j]; }
            } else {
                #pragma unroll
                for (int j = 0; j < 8; ++j) {
                    int k = kb + j;
                    wa4[j] = (k < IN) ? (f16)W4[(size_t)h * IN + k] : (f16)0.f;
                }
            }
            x2a[ht] = MFMA16(wa4, bd, x2a[ht]);
        }
    }
    __syncthreads();  // staging overlay dead beyond this point

    // ---- pre-halved biases (update needs only 2 fma + med3 per element) ----------------------
    f32x4 x2h[2], b2h[2];
    #pragma unroll
    for (int ht = 0; ht < 2; ++ht)
        #pragma unroll
        for (int r = 0; r < 4; ++r) {
            int h = h0 + ht * 16 + q * 4 + r;
            x2h[ht][r] = 0.5f * (x2a[ht][r] + b4[h]);
            b2h[ht][r] = 0.5f * b2[h];
        }

    // fp32 master states in C layout (row h = q*4+r, col m = l16)
    f32x4 s1m[2], s2m[2];
    #pragma unroll
    for (int ht = 0; ht < 2; ++ht)
        #pragma unroll
        for (int r = 0; r < 4; ++r) {
            int h = h0 + ht * 16 + q * 4 + r;
            s1m[ht][r] = s1_in[(size_t)(m0 + l16) * H + h];
            s2m[ht][r] = s2_in[(size_t)(m0 + l16) * H + h];
        }
    f32x4 s0m = {0.f, 0.f, 0.f, 0.f}, b0h = {0.f, 0.f, 0.f, 0.f};
    if (wave == 0) {
        #pragma unroll
        for (int r = 0; r < 4; ++r) {
            int o = q * 4 + r;
            if (o < OUT) { s0m[r] = s0_in[(size_t)(m0 + l16) * OUT + o]; b0h[r] = 0.5f * b0[o]; }
        }
    }

    f16* const s1b[2] = {&pool[OFF_S1_0], &pool[OFF_S1_1]};
    f16* const s2b[2] = {&pool[OFF_S2_0], &pool[OFF_S2_1]};
    f16* const s0b[2] = {&pool[OFF_S0_0], &pool[OFF_S0_1]};

    // conflict-free b64 writeback: 4 consecutive h per lane at stride 33 quads
    auto writeback = [&](f16* ws1, f16* ws2, f16* ws0) {
        #pragma unroll
        for (int ht = 0; ht < 2; ++ht) {
            int hb = h0 + ht * 16 + q * 4;
            f16x4 p1, p2;
            #pragma unroll
            for (int r = 0; r < 4; ++r) { p1[r] = (f16)s1m[ht][r]; p2[r] = (f16)s2m[ht][r]; }
            *(f16x4*)&ws1[l16 * SROW + hb] = p1;
            *(f16x4*)&ws2[l16 * SROW + hb] = p2;
        }
        if (wave == 0) {
            int ob = q * 4;
            if (ob < OUT) {  // q = 0,1,2 ; o=10,11 padded with zeros
                f16x4 p;
                #pragma unroll
                for (int r = 0; r < 4; ++r) p[r] = (ob + r < OUT) ? (f16)s0m[r] : (f16)0.f;
                *(f16x4*)&ws0[l16 * S0ROW + ob] = p;
            }
        }
    };

    auto do_step = [&](const f16* rs1, const f16* rs2, const f16* rs0,
                       f16* ws1, f16* ws2, f16* ws0) {
        f32x4 o1[2] = {{0.f,0.f,0.f,0.f},{0.f,0.f,0.f,0.f}};
        f32x4 o2[2] = {{0.f,0.f,0.f,0.f},{0.f,0.f,0.f,0.f}};
        f32x4 o0    = {0.f,0.f,0.f,0.f};
        #pragma unroll
        for (int kk = 0; kk < 8; ++kk) {
            int kb = kk * 32 + q * 8;
            f16x8 bs1 = *(const f16x8*)&rs1[l16 * SROW + kb];
            f16x8 bs2 = *(const f16x8*)&rs2[l16 * SROW + kb];
            o2[0] = MFMA16(wA[0][kk], bs1, o2[0]);
            o2[1] = MFMA16(wA[1][kk], bs1, o2[1]);
            o1[0] = MFMA16(wB[0][kk], bs2, o1[0]);
            o1[1] = MFMA16(wB[1][kk], bs2, o1[1]);
            if (wave == 0) {
                f16x8 a0 = *(const f16x8*)&pool[OFF_W0N + l16 * SROW + kb];
                o0 = MFMA16(a0, bs1, o0);
            }
        }
        {
            f16x8 bs0 = *(const f16x8*)&rs0[l16 * S0ROW + q * 8];
            o1[0] = MFMA16(w0c[0], bs0, o1[0]);
            o1[1] = MFMA16(w0c[1], bs0, o1[1]);
        }
        #pragma unroll
        for (int ht = 0; ht < 2; ++ht)
            #pragma unroll
            for (int r = 0; r < 4; ++r) {
                s1m[ht][r] = CLAMP01(fmaf(0.5f, s1m[ht][r], fmaf(0.5f, o1[ht][r], b2h[ht][r])));
                s2m[ht][r] = CLAMP01(fmaf(0.5f, s2m[ht][r], fmaf(0.5f, o2[ht][r], x2h[ht][r])));
            }
        if (wave == 0) {
            #pragma unroll
            for (int r = 0; r < 4; ++r)
                s0m[r] = CLAMP01(fmaf(0.5f, s0m[r], fmaf(0.5f, o0[r], b0h[r])));
        }
        writeback(ws1, ws2, ws0);
    };

    writeback(s1b[0], s2b[0], s0b[0]);
    __syncthreads();

    // ---- main loop: one barrier per step via double buffering --------------------------------
    #pragma unroll 1
    for (int t = 0; t < TSTEP; t += 2) {
        do_step(s1b[0], s2b[0], s0b[0], s1b[1], s2b[1], s0b[1]);
        __syncthreads();
        do_step(s1b[1], s2b[1], s0b[1], s1b[0], s2b[0], s0b[0]);
        __syncthreads();
    }

    // ---- epilogue: coalesced output via LDS transpose (overlay on state buffers) --------------
    if (wave == 0) {
        #pragma unroll
        for (int r = 0; r < 4; ++r) {
            int o = q * 4 + r;
            if (o < OUT) out[(size_t)(m0 + l16) * OUT + o] = s0m[r];
        }
    }
    float* xf = (float*)pool;  // [16][264] f32
    float* o1p = out + (size_t)BATCH * OUT;
    float* o2p = o1p + (size_t)BATCH * H;
    #pragma unroll
    for (int ht = 0; ht < 2; ++ht)
        *(f32x4*)&xf[l16 * 264 + h0 + ht * 16 + q * 4] = s1m[ht];
    __syncthreads();
    for (int i = tid; i < BM * H / 4; i += NTHR) {
        int m = i >> 6, c = (i & 63) * 4;
        f32x4 v = *(const f32x4*)&xf[m * 264 + c];
        *(f32x4*)&o1p[(size_t)(m0 + m) * H + c] = v;
    }
    __syncthreads();
    #pragma unroll
    for (int ht = 0; ht < 2; ++ht)
        *(f32x4*)&xf[l16 * 264 + h0 + ht * 16 + q * 4] = s2m[ht];
    __syncthreads();
    for (int i = tid; i < BM * H / 4; i += NTHR) {
        int m = i >> 6, c = (i & 63) * 4;
        f32x4 v = *(const f32x4*)&xf[m * 264 + c];
        *(f32x4*)&o2p[(size_t)(m0 + m) * H + c] = v;
    }
}

extern "C" void kernel_launch(void* const* d_in, const int* in_sizes, int n_in,
                              void* d_out, int out_size, void* d_ws, size_t ws_size,
                              hipStream_t stream) {
    const float* data  = (const float*)d_in[0];
    const float* s0_in = (const float*)d_in[1];
    const float* s1_in = (const float*)d_in[2];
    const float* s2_in = (const float*)d_in[3];
    const float* W0    = (const float*)d_in[4];
    const float* b0    = (const float*)d_in[5];
    const float* W2    = (const float*)d_in[6];
    const float* b2    = (const float*)d_in[7];
    const float* W4    = (const float*)d_in[8];
    const float* b4    = (const float*)d_in[9];
    float* out = (float*)d_out;

    ep_step_kernel<<<BATCH / BM, NTHR, 0, stream>>>(
        data, s0_in, s1_in, s2_in, W0, b0, W2, b2, W4, b4, out);
}

// Round 3
// 579.143 us; speedup vs baseline: 2.9374x; 2.9374x over previous
//
#include <hip/hip_runtime.h>

typedef _Float16 f16;
typedef _Float16 f16x8 __attribute__((ext_vector_type(8)));
typedef _Float16 f16x4 __attribute__((ext_vector_type(4)));
typedef float f32x4 __attribute__((ext_vector_type(4)));

#define MFMA16(a, b, c) __builtin_amdgcn_mfma_f32_16x16x32_f16((a), (b), (c), 0, 0, 0)
#define CLAMP01(x) __builtin_amdgcn_fmed3f((x), 0.0f, 1.0f)

constexpr int BATCH = 16384;
constexpr int H     = 256;
constexpr int IN    = 784;
constexpr int OUT   = 10;
constexpr int TSTEP = 50;
constexpr int BM    = 16;    // batch rows per block
constexpr int NTHR  = 512;   // 8 waves; wave w owns h in [32w, 32w+32)
constexpr int SROW  = 264;   // padded f16 row stride (33 x 16B quads -> conflict-free b128)
constexpr int S0ROW = 40;    // padded f16 row stride for s0 tile (K padded 10->32)
constexpr int DROW  = 808;   // data staging stride: 101 quads (odd) -> conflict-free prologue reads

// LDS pool offsets (f16 units). Data staging [16][808]=12928 f16 overlays the
// state buffers (not yet live during the x2 prologue). Epilogue f32 transpose
// buffer (16x264 f32 = 8448 f16) also overlays the state buffers.
constexpr int OFF_S1_0 = 0;
constexpr int OFF_S1_1 = BM * SROW;            // 4224
constexpr int OFF_S2_0 = 2 * BM * SROW;        // 8448
constexpr int OFF_S2_1 = 3 * BM * SROW;        // 12672
constexpr int OFF_S0_0 = 4 * BM * SROW;        // 16896
constexpr int OFF_S0_1 = OFF_S0_0 + BM * S0ROW;
constexpr int OFF_W0N  = OFF_S0_1 + BM * S0ROW; // 18176
constexpr int POOL_F16 = OFF_W0N + 16 * SROW;   // 22400 f16 = 44800 B

// NOTE: second arg MUST stay 2. With 2 waves/EU the unified VGPR+AGPR budget is
// 256/wave, which the persistent weight fragments (wA+wB+w0c = 136 VGPRs) need.
// (NTHR,4) in R2 capped it at 128 -> weights spilled to scratch -> 4.7 GB HBM fetch, 3x slower.
__global__ __launch_bounds__(NTHR, 2) void ep_step_kernel(
    const float* __restrict__ data, const float* __restrict__ s0_in,
    const float* __restrict__ s1_in, const float* __restrict__ s2_in,
    const float* __restrict__ W0, const float* __restrict__ b0,
    const float* __restrict__ W2, const float* __restrict__ b2,
    const float* __restrict__ W4, const float* __restrict__ b4,
    float* __restrict__ out)
{
    __shared__ __align__(16) f16 pool[POOL_F16];

    const int tid  = threadIdx.x;
    const int wave = tid >> 6;
    const int lane = tid & 63;
    const int q    = lane >> 4;   // quad 0..3
    const int l16  = lane & 15;
    const int m0   = blockIdx.x * BM;
    const int h0   = wave * 32;   // this wave's 32-column h slab (2 tiles of 16)

    // ---- phase 1: stage rho(data)->f16 LDS (overlay), W0-natural tile, zero s0 bufs ----------
    for (int i = tid; i < BM * (DROW / 4); i += NTHR) {
        int m  = i / (DROW / 4);
        int k4 = (i % (DROW / 4)) * 4;
        f16x4 p = {(f16)0.f, (f16)0.f, (f16)0.f, (f16)0.f};
        if (k4 < IN) {
            f32x4 v = *(const f32x4*)(data + (size_t)(m0 + m) * IN + k4);
            #pragma unroll
            for (int j = 0; j < 4; ++j) p[j] = (f16)CLAMP01(v[j]);
        }
        *(f16x4*)&pool[m * DROW + k4] = p;
    }
    for (int i = tid; i < 16 * SROW; i += NTHR) {
        int o = i / SROW, k = i % SROW;
        pool[OFF_W0N + i] = (o < OUT && k < H) ? (f16)W0[o * H + k] : (f16)0.f;
    }
    for (int i = tid; i < 2 * BM * S0ROW; i += NTHR) pool[OFF_S0_0 + i] = (f16)0.f;
    __syncthreads();

    // ---- phase 2: persistent register weight fragments ----------------------------------------
    f16x8 wB[2][8];  // A'[h][k] = W2[h][k]   (for out1 = s2 @ W2^T)
    f16x8 wA[2][8];  // A'[h][k] = W2[k][h]   (for out2 = s1 @ W2)
    #pragma unroll
    for (int ht = 0; ht < 2; ++ht) {
        int h = h0 + ht * 16 + l16;
        #pragma unroll
        for (int kk = 0; kk < 8; ++kk) {
            int kb = kk * 32 + q * 8;
            f32x4 u0 = *(const f32x4*)(W2 + h * H + kb);
            f32x4 u1 = *(const f32x4*)(W2 + h * H + kb + 4);
            f16x8 wb;
            #pragma unroll
            for (int j = 0; j < 4; ++j) { wb[j] = (f16)u0[j]; wb[j + 4] = (f16)u1[j]; }
            wB[ht][kk] = wb;
            f16x8 wa;
            #pragma unroll
            for (int j = 0; j < 8; ++j) wa[j] = (f16)W2[(kb + j) * H + h];
            wA[ht][kk] = wa;
        }
    }
    f16x8 w0c[2];  // A'[h][o] = W0[o][h], K padded 10->32
    #pragma unroll
    for (int ht = 0; ht < 2; ++ht) {
        int h = h0 + ht * 16 + l16;
        #pragma unroll
        for (int j = 0; j < 8; ++j) {
            int o = q * 8 + j;
            w0c[ht][j] = (o < OUT) ? (f16)W0[o * H + h] : (f16)0.f;
        }
    }

    // x2 = rho(data) @ W4^T + b4 (transposed C[h][m]), persistent in registers
    f32x4 x2a[2] = {{0.f, 0.f, 0.f, 0.f}, {0.f, 0.f, 0.f, 0.f}};
    for (int kk = 0; kk < 25; ++kk) {
        int kb = kk * 32 + q * 8;
        f16x8 bd = *(const f16x8*)&pool[l16 * DROW + kb];
        #pragma unroll
        for (int ht = 0; ht < 2; ++ht) {
            int h = h0 + ht * 16 + l16;
            f16x8 wa4;
            if (kk < 24) {
                f32x4 u0 = *(const f32x4*)(W4 + (size_t)h * IN + kb);
                f32x4 u1 = *(const f32x4*)(W4 + (size_t)h * IN + kb + 4);
                #pragma unroll
                for (int j = 0; j < 4; ++j) { wa4[j] = (f16)u0[j]; wa4[j + 4] = (f16)u1[j]; }
            } else {
                #pragma unroll
                for (int j = 0; j < 8; ++j) {
                    int k = kb + j;
                    wa4[j] = (k < IN) ? (f16)W4[(size_t)h * IN + k] : (f16)0.f;
                }
            }
            x2a[ht] = MFMA16(wa4, bd, x2a[ht]);
        }
    }
    __syncthreads();  // staging overlay dead beyond this point

    // ---- pre-halved biases (update needs only 2 fma + med3 per element) ----------------------
    f32x4 x2h[2], b2h[2];
    #pragma unroll
    for (int ht = 0; ht < 2; ++ht)
        #pragma unroll
        for (int r = 0; r < 4; ++r) {
            int h = h0 + ht * 16 + q * 4 + r;
            x2h[ht][r] = 0.5f * (x2a[ht][r] + b4[h]);
            b2h[ht][r] = 0.5f * b2[h];
        }

    // fp32 master states in C layout (row h = q*4+r, col m = l16)
    f32x4 s1m[2], s2m[2];
    #pragma unroll
    for (int ht = 0; ht < 2; ++ht)
        #pragma unroll
        for (int r = 0; r < 4; ++r) {
            int h = h0 + ht * 16 + q * 4 + r;
            s1m[ht][r] = s1_in[(size_t)(m0 + l16) * H + h];
            s2m[ht][r] = s2_in[(size_t)(m0 + l16) * H + h];
        }
    f32x4 s0m = {0.f, 0.f, 0.f, 0.f}, b0h = {0.f, 0.f, 0.f, 0.f};
    if (wave == 0) {
        #pragma unroll
        for (int r = 0; r < 4; ++r) {
            int o = q * 4 + r;
            if (o < OUT) { s0m[r] = s0_in[(size_t)(m0 + l16) * OUT + o]; b0h[r] = 0.5f * b0[o]; }
        }
    }

    f16* const s1b[2] = {&pool[OFF_S1_0], &pool[OFF_S1_1]};
    f16* const s2b[2] = {&pool[OFF_S2_0], &pool[OFF_S2_1]};
    f16* const s0b[2] = {&pool[OFF_S0_0], &pool[OFF_S0_1]};

    // conflict-free b64 writeback: 4 consecutive h per lane at stride 33 quads
    auto writeback = [&](f16* ws1, f16* ws2, f16* ws0) {
        #pragma unroll
        for (int ht = 0; ht < 2; ++ht) {
            int hb = h0 + ht * 16 + q * 4;
            f16x4 p1, p2;
            #pragma unroll
            for (int r = 0; r < 4; ++r) { p1[r] = (f16)s1m[ht][r]; p2[r] = (f16)s2m[ht][r]; }
            *(f16x4*)&ws1[l16 * SROW + hb] = p1;
            *(f16x4*)&ws2[l16 * SROW + hb] = p2;
        }
        if (wave == 0) {
            int ob = q * 4;
            if (ob < OUT) {  // q = 0,1,2 ; o=10,11 padded with zeros
                f16x4 p;
                #pragma unroll
                for (int r = 0; r < 4; ++r) p[r] = (ob + r < OUT) ? (f16)s0m[r] : (f16)0.f;
                *(f16x4*)&ws0[l16 * S0ROW + ob] = p;
            }
        }
    };

    auto do_step = [&](const f16* rs1, const f16* rs2, const f16* rs0,
                       f16* ws1, f16* ws2, f16* ws0) {
        f32x4 o1[2] = {{0.f,0.f,0.f,0.f},{0.f,0.f,0.f,0.f}};
        f32x4 o2[2] = {{0.f,0.f,0.f,0.f},{0.f,0.f,0.f,0.f}};
        f32x4 o0    = {0.f,0.f,0.f,0.f};
        #pragma unroll
        for (int kk = 0; kk < 8; ++kk) {
            int kb = kk * 32 + q * 8;
            f16x8 bs1 = *(const f16x8*)&rs1[l16 * SROW + kb];
            f16x8 bs2 = *(const f16x8*)&rs2[l16 * SROW + kb];
            o2[0] = MFMA16(wA[0][kk], bs1, o2[0]);
            o2[1] = MFMA16(wA[1][kk], bs1, o2[1]);
            o1[0] = MFMA16(wB[0][kk], bs2, o1[0]);
            o1[1] = MFMA16(wB[1][kk], bs2, o1[1]);
            if (wave == 0) {
                f16x8 a0 = *(const f16x8*)&pool[OFF_W0N + l16 * SROW + kb];
                o0 = MFMA16(a0, bs1, o0);
            }
        }
        {
            f16x8 bs0 = *(const f16x8*)&rs0[l16 * S0ROW + q * 8];
            o1[0] = MFMA16(w0c[0], bs0, o1[0]);
            o1[1] = MFMA16(w0c[1], bs0, o1[1]);
        }
        #pragma unroll
        for (int ht = 0; ht < 2; ++ht)
            #pragma unroll
            for (int r = 0; r < 4; ++r) {
                s1m[ht][r] = CLAMP01(fmaf(0.5f, s1m[ht][r], fmaf(0.5f, o1[ht][r], b2h[ht][r])));
                s2m[ht][r] = CLAMP01(fmaf(0.5f, s2m[ht][r], fmaf(0.5f, o2[ht][r], x2h[ht][r])));
            }
        if (wave == 0) {
            #pragma unroll
            for (int r = 0; r < 4; ++r)
                s0m[r] = CLAMP01(fmaf(0.5f, s0m[r], fmaf(0.5f, o0[r], b0h[r])));
        }
        writeback(ws1, ws2, ws0);
    };

    writeback(s1b[0], s2b[0], s0b[0]);
    __syncthreads();

    // ---- main loop: one barrier per step via double buffering --------------------------------
    #pragma unroll 1
    for (int t = 0; t < TSTEP; t += 2) {
        do_step(s1b[0], s2b[0], s0b[0], s1b[1], s2b[1], s0b[1]);
        __syncthreads();
        do_step(s1b[1], s2b[1], s0b[1], s1b[0], s2b[0], s0b[0]);
        __syncthreads();
    }

    // ---- epilogue: coalesced output via LDS transpose (overlay on state buffers) --------------
    if (wave == 0) {
        #pragma unroll
        for (int r = 0; r < 4; ++r) {
            int o = q * 4 + r;
            if (o < OUT) out[(size_t)(m0 + l16) * OUT + o] = s0m[r];
        }
    }
    float* xf = (float*)pool;  // [16][264] f32
    float* o1p = out + (size_t)BATCH * OUT;
    float* o2p = o1p + (size_t)BATCH * H;
    #pragma unroll
    for (int ht = 0; ht < 2; ++ht)
        *(f32x4*)&xf[l16 * 264 + h0 + ht * 16 + q * 4] = s1m[ht];
    __syncthreads();
    for (int i = tid; i < BM * H / 4; i += NTHR) {
        int m = i >> 6, c = (i & 63) * 4;
        f32x4 v = *(const f32x4*)&xf[m * 264 + c];
        *(f32x4*)&o1p[(size_t)(m0 + m) * H + c] = v;
    }
    __syncthreads();
    #pragma unroll
    for (int ht = 0; ht < 2; ++ht)
        *(f32x4*)&xf[l16 * 264 + h0 + ht * 16 + q * 4] = s2m[ht];
    __syncthreads();
    for (int i = tid; i < BM * H / 4; i += NTHR) {
        int m = i >> 6, c = (i & 63) * 4;
        f32x4 v = *(const f32x4*)&xf[m * 264 + c];
        *(f32x4*)&o2p[(size_t)(m0 + m) * H + c] = v;
    }
}

extern "C" void kernel_launch(void* const* d_in, const int* in_sizes, int n_in,
                              void* d_out, int out_size, void* d_ws, size_t ws_size,
                              hipStream_t stream) {
    const float* data  = (const float*)d_in[0];
    const float* s0_in = (const float*)d_in[1];
    const float* s1_in = (const float*)d_in[2];
    const float* s2_in = (const float*)d_in[3];
    const float* W0    = (const float*)d_in[4];
    const float* b0    = (const float*)d_in[5];
    const float* W2    = (const float*)d_in[6];
    const float* b2    = (const float*)d_in[7];
    const float* W4    = (const float*)d_in[8];
    const float* b4    = (const float*)d_in[9];
    float* out = (float*)d_out;

    ep_step_kernel<<<BATCH / BM, NTHR, 0, stream>>>(
        data, s0_in, s1_in, s2_in, W0, b0, W2, b2, W4, b4, out);
}